// Round 6
// baseline (139.259 us; speedup 1.0000x reference)
//
#include <hip/hip_runtime.h>
#include <hip/hip_bf16.h>

// Problem: B=32, S=512, P=512, D=768
//   M = B*S = 16384 tokens, N = P = 512 prototypes, K = D = 768
// out[0 .. M*N)            = distances  ||x_m - p_n||^2  (fp32)
// out[M*N .. M*N + N*K)    = prototypes (fp32 passthrough)
//
// R6: R5's barrier-free K-loop + 3x resident parallelism.
//   prep_b: prototypes fp32 -> b_bf (bf16 ws) + p_sq + fp32 passthrough.
//   dist_main: grid 1024 (4 per CU dispatch slack, ~3 resident via LDS),
//     256 thr (4 waves), block tile 32 rows x 256 cols.
//     - A stripe (32 x 768) staged ONCE into padded LDS (48.5 KB -> 3 blocks/CU),
//       x_sq computed in fp32 during staging. ONE barrier total.
//     - per wave: 32x64 tile, B frags loaded global->VGPR (bf16, L2-hot),
//       software-pipelined one chunk ahead (partial vmcnt waits, no drain).
//     - 2x4 mfma_f32_16x16x32_bf16 per chunk, 24 chunks.
//     - epilogue: out = x_sq + p_sq - 2*acc.

#define M_TOK 16384
#define N_PROT 512
#define K_DIM 768
#define BK 32
#define NCH (K_DIM / BK)     // 24
#define ASTR (K_DIM + 8)     // 776: padded LDS row stride in bf16 units

typedef __attribute__((ext_vector_type(4))) float f32x4;
typedef __attribute__((ext_vector_type(8))) short bf16x8;

__device__ inline unsigned short f2bf(float f) {
    // round-to-nearest-even on the bit pattern (finite inputs)
    unsigned int u = __float_as_uint(f);
    u += 0x7fffu + ((u >> 16) & 1u);
    return (unsigned short)(u >> 16);
}

// One wave per prototype row: bf16 convert + ||p||^2 + fp32 passthrough copy.
__global__ __launch_bounds__(256) void prep_b(
    const float* __restrict__ p,
    unsigned short* __restrict__ b_bf, float* __restrict__ p_sq,
    float* __restrict__ proto_out)
{
    const int row  = blockIdx.x * 4 + (threadIdx.x >> 6);
    const int lane = threadIdx.x & 63;

    const float4* src4 = (const float4*)(p + (size_t)row * K_DIM);
    unsigned short* dst = b_bf + (size_t)row * K_DIM;
    float4* pout4 = (float4*)(proto_out + (size_t)row * K_DIM);

    float ssum = 0.0f;
#pragma unroll
    for (int j = 0; j < 3; ++j) {        // 192 float4 per row / 64 lanes
        const int idx = lane + j * 64;
        float4 v = src4[idx];
        ssum += v.x * v.x + v.y * v.y + v.z * v.z + v.w * v.w;
        ushort4 b;
        b.x = f2bf(v.x); b.y = f2bf(v.y); b.z = f2bf(v.z); b.w = f2bf(v.w);
        ((ushort4*)dst)[idx] = b;
        pout4[idx] = v;
    }
#pragma unroll
    for (int off = 32; off > 0; off >>= 1) ssum += __shfl_down(ssum, off);
    if (lane == 0) p_sq[row] = ssum;
}

__global__ __launch_bounds__(256, 3) void dist_main(
    const float* __restrict__ X,             // [M,K] fp32 tokens
    const unsigned short* __restrict__ Bb,   // [N,K] bf16 prototypes (ws)
    const float* __restrict__ p_sq,          // [N] fp32
    float* __restrict__ out)                 // [M,N] fp32 distances
{
    __shared__ unsigned short lds_a[32 * ASTR];   // 48.5 KB, full-K A stripe
    __shared__ float lds_xsq[32];

    const int tid  = threadIdx.x;
    const int wave = tid >> 6;                    // 0..3
    const int lane = tid & 63;
    const int bm   = (blockIdx.x >> 1) << 5;      // 32-row A stripe
    const int bn   = (blockIdx.x & 1) << 8;       // 256-col N half
    const int wn   = bn + (wave << 6);            // this wave's 64-col slice
    const int quad = lane >> 4;                   // 0..3
    const int l16  = lane & 15;

    // ---- one-time A staging: fp32 -> (x_sq, bf16 LDS) ----
    const int ar = tid >> 3;             // 0..31 row
    const int ac = tid & 7;              // float4 col base
    const float* aptr = X + (size_t)(bm + ar) * K_DIM;
    float asq = 0.0f;
#pragma unroll
    for (int j = 0; j < 24; ++j) {
        const int c4 = ac + 8 * j;       // float4 index 0..191
        float4 v = *(const float4*)(aptr + (size_t)c4 * 4);
        asq += v.x * v.x + v.y * v.y + v.z * v.z + v.w * v.w;
        ushort4 u;
        u.x = f2bf(v.x); u.y = f2bf(v.y); u.z = f2bf(v.z); u.w = f2bf(v.w);
        *(ushort4*)&lds_a[ar * ASTR + c4 * 4] = u;
    }
#pragma unroll
    for (int off = 1; off < 8; off <<= 1) asq += __shfl_xor(asq, off);
    if (ac == 0) lds_xsq[ar] = asq;

    __syncthreads();   // the ONLY barrier

    // ---- barrier-free K-loop: wave tile 32 x 64, 2x4 MFMA frags ----
    const f32x4 zero = {0.0f, 0.0f, 0.0f, 0.0f};
    f32x4 acc[2][4];
#pragma unroll
    for (int mt = 0; mt < 2; ++mt)
#pragma unroll
        for (int nt = 0; nt < 4; ++nt) acc[mt][nt] = zero;

    // per-lane B fragment pointer: row (wn + nt*16 + l16), 16B chunk at quad*8
    const unsigned short* bp = Bb + (size_t)(wn + l16) * K_DIM + quad * 8;

    bf16x8 bcur[4], bnxt[4];
#pragma unroll
    for (int nt = 0; nt < 4; ++nt)
        bcur[nt] = *(const bf16x8*)(bp + (size_t)(nt * 16) * K_DIM);

    for (int kc = 0; kc < NCH; ++kc) {
        const int k0 = kc * BK;
        if (kc + 1 < NCH) {
#pragma unroll
            for (int nt = 0; nt < 4; ++nt)
                bnxt[nt] = *(const bf16x8*)(bp + (size_t)(nt * 16) * K_DIM + k0 + BK);
        }

        bf16x8 af[2];
#pragma unroll
        for (int mt = 0; mt < 2; ++mt)
            af[mt] = *(const bf16x8*)&lds_a[(mt * 16 + l16) * ASTR + k0 + quad * 8];

#pragma unroll
        for (int mt = 0; mt < 2; ++mt)
#pragma unroll
            for (int nt = 0; nt < 4; ++nt)
                acc[mt][nt] = __builtin_amdgcn_mfma_f32_16x16x32_bf16(
                    af[mt], bcur[nt], acc[mt][nt], 0, 0, 0);

#pragma unroll
        for (int nt = 0; nt < 4; ++nt) bcur[nt] = bnxt[nt];
    }

    // ---- epilogue: C/D layout col = lane&15, row = quad*4 + i ----
    float ps[4];
#pragma unroll
    for (int nt = 0; nt < 4; ++nt) ps[nt] = p_sq[wn + nt * 16 + l16];

#pragma unroll
    for (int mt = 0; mt < 2; ++mt) {
#pragma unroll
        for (int i = 0; i < 4; ++i) {
            const int lr = mt * 16 + quad * 4 + i;   // local row 0..31
            const float xs = lds_xsq[lr];
            float* orow = out + (size_t)(bm + lr) * N_PROT + wn + l16;
#pragma unroll
            for (int nt = 0; nt < 4; ++nt)
                orow[nt * 16] = xs + ps[nt] - 2.0f * acc[mt][nt][i];
        }
    }
}

extern "C" void kernel_launch(void* const* d_in, const int* in_sizes, int n_in,
                              void* d_out, int out_size, void* d_ws, size_t ws_size,
                              hipStream_t stream) {
    const float* inputs = (const float*)d_in[0];   // [32,512,768] fp32
    const float* protos = (const float*)d_in[1];   // [512,768]    fp32
    float* out = (float*)d_out;
    float* proto_out = out + (size_t)M_TOK * N_PROT;   // second tuple element

    // ws layout: b_bf 512*768*2 = 786,432 B ; p_sq 512*4 = 2,048 B
    char* ws = (char*)d_ws;
    unsigned short* b_bf = (unsigned short*)ws;
    float* p_sq = (float*)(ws + 786432);

    prep_b<<<128, 256, 0, stream>>>(protos, b_bf, p_sq, proto_out);
    // grid: (M/32) * (N/256) = 512 * 2 = 1024 blocks
    dist_main<<<1024, 256, 0, stream>>>(inputs, b_bf, p_sq, out);
}

// Round 7
// 117.179 us; speedup vs baseline: 1.1884x; 1.1884x over previous
//
#include <hip/hip_runtime.h>
#include <hip/hip_bf16.h>

// Problem: B=32, S=512, P=512, D=768
//   M = B*S = 16384 tokens, N = P = 512 prototypes, K = D = 768
// out[0 .. M*N)            = distances  ||x_m - p_n||^2  (fp32)
// out[M*N .. M*N + N*K)    = prototypes (fp32 passthrough)
//
// R7: split structure (best so far), both halves tuned.
//   prep: 2 rows per wave, 6 batched float4 loads (deep MLP), fp32->bf16 +
//         exact fp32 norms + proto passthrough. ~82 MB => ~13 us floor.
//   gemm: m97-verified 128x128xBK64 2-barrier K-loop, global_load_lds w16,
//         PLUS the two things R2 lacked vs m97's 874 TF config:
//         (a) 3 blocks/CU residency (__launch_bounds__(256,3), 32 KB LDS)
//             so other blocks' MFMA covers each block's barrier drain (m114);
//         (b) XCD-aware swizzle bn=bid>>7 -> one 196 KB B-tile per XCD epoch
//             (B L2-resident), A streamed once.

#define M_TOK 16384
#define N_PROT 512
#define K_DIM 768

typedef __attribute__((ext_vector_type(4))) float f32x4;
typedef __attribute__((ext_vector_type(8))) short bf16x8;

typedef const __attribute__((address_space(1))) unsigned int g_uint;
typedef __attribute__((address_space(3))) unsigned int l_uint;

__device__ inline unsigned short f2bf(float f) {
    // round-to-nearest-even on the bit pattern (finite inputs)
    unsigned int u = __float_as_uint(f);
    u += 0x7fffu + ((u >> 16) & 1u);
    return (unsigned short)(u >> 16);
}

// Two rows per wave: 6 independent float4 loads batched per lane.
// Rows [0, M_TOK) = tokens -> a_bf + x_sq.
// Rows [M_TOK, 16896) = prototypes -> b_bf + p_sq + fp32 passthrough.
__global__ __launch_bounds__(256) void prep_kernel(
    const float* __restrict__ x, const float* __restrict__ p,
    unsigned short* __restrict__ a_bf, unsigned short* __restrict__ b_bf,
    float* __restrict__ x_sq, float* __restrict__ p_sq,
    float* __restrict__ proto_out)
{
    const int gw   = blockIdx.x * 4 + (threadIdx.x >> 6);  // global wave id
    const int lane = threadIdx.x & 63;

    float4 v[2][3];
    const float4* src4[2];
    unsigned short* dst[2];
    float4* pout4[2];
    int rows[2];

#pragma unroll
    for (int r = 0; r < 2; ++r) {
        const int row = gw * 2 + r;       // pairs never straddle 16384 (even)
        rows[r] = row;
        if (row < M_TOK) {
            src4[r]  = (const float4*)(x + (size_t)row * K_DIM);
            dst[r]   = a_bf + (size_t)row * K_DIM;
            pout4[r] = nullptr;
        } else {
            const int pr = row - M_TOK;
            src4[r]  = (const float4*)(p + (size_t)pr * K_DIM);
            dst[r]   = b_bf + (size_t)pr * K_DIM;
            pout4[r] = (float4*)(proto_out + (size_t)pr * K_DIM);
        }
    }

    // issue all 6 loads before any use
#pragma unroll
    for (int r = 0; r < 2; ++r)
#pragma unroll
        for (int j = 0; j < 3; ++j)
            v[r][j] = src4[r][lane + j * 64];

    float ss[2];
#pragma unroll
    for (int r = 0; r < 2; ++r) {
        ss[r] = 0.0f;
#pragma unroll
        for (int j = 0; j < 3; ++j) {
            const int idx = lane + j * 64;
            float4 w = v[r][j];
            ss[r] += w.x * w.x + w.y * w.y + w.z * w.z + w.w * w.w;
            ushort4 b;
            b.x = f2bf(w.x); b.y = f2bf(w.y); b.z = f2bf(w.z); b.w = f2bf(w.w);
            ((ushort4*)dst[r])[idx] = b;
            if (pout4[r]) pout4[r][idx] = w;
        }
#pragma unroll
        for (int off = 32; off > 0; off >>= 1) ss[r] += __shfl_down(ss[r], off);
    }

    if (lane == 0) {
#pragma unroll
        for (int r = 0; r < 2; ++r) {
            if (rows[r] < M_TOK) x_sq[rows[r]] = ss[r];
            else                 p_sq[rows[r] - M_TOK] = ss[r];
        }
    }
}

// 128x128 block tile, BK=64 (12 K-iterations, 32 MFMA per barrier pair),
// 4 waves in 2x2, each wave 64x64 via 4x4 mfma_f32_16x16x32_bf16.
// 3 blocks/CU resident; XCD-friendly swizzle bn=bid>>7.
__global__ __launch_bounds__(256, 3) void gemm_kernel(
    const unsigned short* __restrict__ A,   // [M,K] bf16
    const unsigned short* __restrict__ Bt,  // [N,K] bf16 (prototypes, row-major = B^T)
    const float* __restrict__ x_sq, const float* __restrict__ p_sq,
    float* __restrict__ out)                // [M,N] fp32
{
    __shared__ unsigned short lds_a[128 * 64];   // 16 KB
    __shared__ unsigned short lds_b[128 * 64];   // 16 KB

    const int tid  = threadIdx.x;
    const int wave = tid >> 6;
    const int lane = tid & 63;
    const int bid  = blockIdx.x;
    const int bn = (bid >> 7) << 7;    // 0..3 -> B tile; 128 consecutive bids share it
    const int bm = (bid & 127) << 7;
    const int wm = (wave >> 1) << 6;   // wave row offset in block tile
    const int wn = (wave & 1) << 6;    // wave col offset
    const int quad = lane >> 4;        // 0..3
    const int l16  = lane & 15;

    // staging geometry: each wave stages 32 rows of A-tile and 32 rows of B-tile.
    // One global_load_lds: 64 lanes x 16B = 1024 B = 8 rows x 128 B/row.
    const int srow  = wave * 32;
    const int lrow8 = lane >> 3;           // 0..7 (row within 8-row chunk)
    const int lcol  = (lane & 7) * 8;      // ushort offset of this lane's 16B chunk

    const f32x4 zero = {0.0f, 0.0f, 0.0f, 0.0f};
    f32x4 acc[4][4];
#pragma unroll
    for (int mt = 0; mt < 4; ++mt)
#pragma unroll
        for (int nt = 0; nt < 4; ++nt) acc[mt][nt] = zero;

    for (int k0 = 0; k0 < K_DIM; k0 += 64) {
        __syncthreads();   // previous iteration's ds_reads complete before overwrite
#pragma unroll
        for (int i = 0; i < 4; ++i) {
            const unsigned short* ga =
                A + (size_t)(bm + srow + i * 8 + lrow8) * K_DIM + k0 + lcol;
            __builtin_amdgcn_global_load_lds((g_uint*)ga,
                (l_uint*)&lds_a[(srow + i * 8) * 64], 16, 0, 0);
            const unsigned short* gb =
                Bt + (size_t)(bn + srow + i * 8 + lrow8) * K_DIM + k0 + lcol;
            __builtin_amdgcn_global_load_lds((g_uint*)gb,
                (l_uint*)&lds_b[(srow + i * 8) * 64], 16, 0, 0);
        }
        __syncthreads();   // drains vmcnt(0): staged tile visible

        bf16x8 af[2][4], bfr[2][4];
#pragma unroll
        for (int ks = 0; ks < 2; ++ks) {
#pragma unroll
            for (int mt = 0; mt < 4; ++mt)
                af[ks][mt] = *(const bf16x8*)
                    &lds_a[(wm + mt * 16 + l16) * 64 + ks * 32 + quad * 8];
#pragma unroll
            for (int nt = 0; nt < 4; ++nt)
                bfr[ks][nt] = *(const bf16x8*)
                    &lds_b[(wn + nt * 16 + l16) * 64 + ks * 32 + quad * 8];
        }

#pragma unroll
        for (int ks = 0; ks < 2; ++ks)
#pragma unroll
            for (int mt = 0; mt < 4; ++mt)
#pragma unroll
                for (int nt = 0; nt < 4; ++nt)
                    acc[mt][nt] = __builtin_amdgcn_mfma_f32_16x16x32_bf16(
                        af[ks][mt], bfr[ks][nt], acc[mt][nt], 0, 0, 0);
    }

    // Epilogue: C/D layout col = lane&15, row = quad*4 + i
    float ps[4];
#pragma unroll
    for (int nt = 0; nt < 4; ++nt) ps[nt] = p_sq[bn + wn + nt * 16 + l16];

#pragma unroll
    for (int mt = 0; mt < 4; ++mt) {
#pragma unroll
        for (int i = 0; i < 4; ++i) {
            const int gr = bm + wm + mt * 16 + quad * 4 + i;
            const float xs = x_sq[gr];
            float* orow = out + (size_t)gr * N_PROT + bn + wn + l16;
#pragma unroll
            for (int nt = 0; nt < 4; ++nt)
                orow[nt * 16] = xs + ps[nt] - 2.0f * acc[mt][nt][i];
        }
    }
}

extern "C" void kernel_launch(void* const* d_in, const int* in_sizes, int n_in,
                              void* d_out, int out_size, void* d_ws, size_t ws_size,
                              hipStream_t stream) {
    const float* inputs = (const float*)d_in[0];   // [32,512,768] fp32
    const float* protos = (const float*)d_in[1];   // [512,768]    fp32
    float* out = (float*)d_out;

    // workspace layout (all 16B-aligned):
    //   a_bf : M*K bf16 = 25,165,824 B
    //   b_bf : N*K bf16 =    786,432 B
    //   x_sq : M fp32   =     65,536 B
    //   p_sq : N fp32   =      2,048 B
    char* ws = (char*)d_ws;
    unsigned short* a_bf = (unsigned short*)ws;
    unsigned short* b_bf = (unsigned short*)(ws + 25165824);
    float* x_sq = (float*)(ws + 25165824 + 786432);
    float* p_sq = (float*)(ws + 25165824 + 786432 + 65536);
    float* proto_out = out + (size_t)M_TOK * N_PROT;   // second tuple element

    // 16896 rows / 2 rows-per-wave / 4 waves-per-block = 2112 blocks
    prep_kernel<<<2112, 256, 0, stream>>>(inputs, protos, a_bf, b_bf, x_sq, p_sq, proto_out);

    gemm_kernel<<<512, 256, 0, stream>>>(a_bf, b_bf, x_sq, p_sq, out);
}